// Round 5
// baseline (378.542 us; speedup 1.0000x reference)
//
#include <hip/hip_runtime.h>
#include <hip/hip_bf16.h>

#define D 512
#define NSEQ 2048
#define NB 8
#define QBLK 32
#define KVBLK 64
#define NTHREADS 512
#define NT (NSEQ / KVBLK)          // 32 kv tiles
#define ROWE 2056                  // v3 layout: elems per kv-group row
#define BUFE (16 * ROWE)
#define SROWP (KVBLK + 4)          // f32 row for Ss
#define PROWP (KVBLK + 8)          // bf16 row for Ps
#define CROWP 68                   // conv transpose tile stride (u16)

typedef __attribute__((ext_vector_type(8))) short bf16x8;
typedef __attribute__((ext_vector_type(4))) float f32x4;
typedef __attribute__((ext_vector_type(4))) unsigned short u16x4;

static __device__ __forceinline__ unsigned short f2b(float f) {
  unsigned u = __builtin_bit_cast(unsigned, f);
  return (unsigned short)((u + 0x7FFFu + ((u >> 16) & 1u)) >> 16);
}

// ---------------- conv: fp32 B -> b16 [kv][d] (memory-bound) ----------------
__global__ __launch_bounds__(256) void conv_b16(const float* __restrict__ in,
                                                unsigned short* __restrict__ out) {
  size_t i = ((size_t)blockIdx.x * 256 + threadIdx.x) * 8;
  float4 v0 = *reinterpret_cast<const float4*>(in + i);
  float4 v1 = *reinterpret_cast<const float4*>(in + i + 4);
  bf16x8 h;
  h[0] = (short)f2b(v0.x); h[1] = (short)f2b(v0.y);
  h[2] = (short)f2b(v0.z); h[3] = (short)f2b(v0.w);
  h[4] = (short)f2b(v1.x); h[5] = (short)f2b(v1.y);
  h[6] = (short)f2b(v1.z); h[7] = (short)f2b(v1.w);
  *reinterpret_cast<bf16x8*>(out + i) = h;
}

// ------- conv: fp32 B -> b16 [kv][d] AND b16T [d][kv] (64x64 LDS tiles) -----
__global__ __launch_bounds__(256) void conv_dual(const float* __restrict__ in,
                                                 unsigned short* __restrict__ b16,
                                                 unsigned short* __restrict__ bT) {
  __shared__ unsigned short tile[64 * CROWP];
  const int bid = blockIdx.x;
  const int batch = bid >> 8;
  const int rem = bid & 255;
  const int kvt = rem >> 3;      // 0..31
  const int dt  = rem & 7;       // 0..7
  const int t = threadIdx.x;
  const int r = t >> 2;          // 0..63 (kv row in tile)
  const int c = (t & 3) * 16;    // d col in tile

  const float* src = in + ((size_t)batch * NSEQ + kvt * 64 + r) * D + dt * 64 + c;
  unsigned short* o16 = b16 + ((size_t)batch * NSEQ + kvt * 64 + r) * D + dt * 64 + c;

  float4 v0 = *reinterpret_cast<const float4*>(src);
  float4 v1 = *reinterpret_cast<const float4*>(src + 4);
  float4 v2 = *reinterpret_cast<const float4*>(src + 8);
  float4 v3 = *reinterpret_cast<const float4*>(src + 12);
  bf16x8 h0, h1;
  h0[0] = (short)f2b(v0.x); h0[1] = (short)f2b(v0.y);
  h0[2] = (short)f2b(v0.z); h0[3] = (short)f2b(v0.w);
  h0[4] = (short)f2b(v1.x); h0[5] = (short)f2b(v1.y);
  h0[6] = (short)f2b(v1.z); h0[7] = (short)f2b(v1.w);
  h1[0] = (short)f2b(v2.x); h1[1] = (short)f2b(v2.y);
  h1[2] = (short)f2b(v2.z); h1[3] = (short)f2b(v2.w);
  h1[4] = (short)f2b(v3.x); h1[5] = (short)f2b(v3.y);
  h1[6] = (short)f2b(v3.z); h1[7] = (short)f2b(v3.w);
  *reinterpret_cast<bf16x8*>(o16)     = h0;
  *reinterpret_cast<bf16x8*>(o16 + 8) = h1;
  #pragma unroll
  for (int i = 0; i < 4; ++i) {
    u16x4 w;
    w[0] = (unsigned short)((i < 2 ? h0 : h1)[(i & 1) * 4 + 0]);
    w[1] = (unsigned short)((i < 2 ? h0 : h1)[(i & 1) * 4 + 1]);
    w[2] = (unsigned short)((i < 2 ? h0 : h1)[(i & 1) * 4 + 2]);
    w[3] = (unsigned short)((i < 2 ? h0 : h1)[(i & 1) * 4 + 3]);
    *reinterpret_cast<u16x4*>(&tile[r * CROWP + c + i * 4]) = w;
  }
  __syncthreads();

  // phase 2: wave w owns kv chunk w*16..+15; lane dr = d row 0..63
  const int w  = t >> 6;
  const int dr = t & 63;
  unsigned short* oT = bT + (size_t)batch * D * NSEQ
                          + (size_t)(dt * 64 + dr) * NSEQ + kvt * 64 + w * 16;
  unsigned short g[16];
  #pragma unroll
  for (int i = 0; i < 16; ++i)
    g[i] = tile[(w * 16 + i) * CROWP + dr];   // all 32 banks per instr
  bf16x8 p0, p1;
  #pragma unroll
  for (int i = 0; i < 8; ++i) { p0[i] = (short)g[i]; p1[i] = (short)g[8 + i]; }
  *reinterpret_cast<bf16x8*>(oT)     = p0;
  *reinterpret_cast<bf16x8*>(oT + 8) = p1;
}

// ---------------------------- v5 main kernel --------------------------------
// Identical to v4 except __launch_bounds__(NTHREADS, 1):
//   (NTHREADS,2) on a 512-thread block = min 2 waves/EU = VGPR cap 128, but
//   live state (qf 64 + kf 64 + acc 32 + temps) needs ~190 -> ~60 regs spilled
//   to scratch (r4: WRITE_SIZE +11MB over output, both pipes idle). Occupancy
//   is LDS-limited at 1 block/CU regardless, so relaxing the cap costs nothing.
__global__ __launch_bounds__(NTHREADS, 1)
void attn_v5(const float* __restrict__ A, const unsigned short* __restrict__ K16,
             const unsigned short* __restrict__ T16, float* __restrict__ Out) {
  __shared__ __align__(16) unsigned short Bt[2][D * KVBLK];   // 2 x 65536 B
  __shared__ float Ss[QBLK * SROWP];
  __shared__ unsigned short Ps[QBLK * PROWP];
  __shared__ float mS[QBLK];
  __shared__ float lS[QBLK];
  __shared__ float aS[QBLK];

  const int tid  = threadIdx.x;
  const int wid  = tid >> 6;
  const int lane = tid & 63;
  const int l16  = lane & 15;
  const int g4   = lane >> 4;

  const int batch = blockIdx.x & 7;       // batch -> XCD
  const int qt    = blockIdx.x >> 3;
  const int qbase = qt * QBLK;

  const float*          Ab = A   + (size_t)batch * NSEQ * D;
  const unsigned short* Kb = K16 + (size_t)batch * NSEQ * D;
  const unsigned short* Tb = T16 + (size_t)batch * D * NSEQ;
  float*                Ob = Out + (size_t)batch * NSEQ * D;

  const float scale = 0.04419417382415922f;  // 1/sqrt(512)

  const int qi = wid >> 2;   // q 16-tile for QK^T
  const int ki = wid & 3;    // kv 16-tile for QK^T

  // ---- Q frags (pre-scaled) ----
  const float* Arow = Ab + (size_t)(qbase + qi * 16 + l16) * D;
  bf16x8 qf[16];
  #pragma unroll
  for (int ks = 0; ks < 16; ++ks) {
    int d0 = ks * 32 + g4 * 8;
    float4 v0 = *reinterpret_cast<const float4*>(Arow + d0);
    float4 v1 = *reinterpret_cast<const float4*>(Arow + d0 + 4);
    bf16x8 f;
    f[0] = (short)f2b(v0.x * scale); f[1] = (short)f2b(v0.y * scale);
    f[2] = (short)f2b(v0.z * scale); f[3] = (short)f2b(v0.w * scale);
    f[4] = (short)f2b(v1.x * scale); f[5] = (short)f2b(v1.y * scale);
    f[6] = (short)f2b(v1.z * scale); f[7] = (short)f2b(v1.w * scale);
    qf[ks] = f;
  }

  // ---- K frags, tile 0 (from b16 [kv][d]) ----
  const unsigned short* kptr = Kb + (size_t)(ki * 16 + l16) * D + g4 * 8;
  bf16x8 kf[16];
  #pragma unroll
  for (int ks = 0; ks < 16; ++ks)
    kf[ks] = *reinterpret_cast<const bf16x8*>(kptr + ks * 32);

  if (tid < QBLK) { mS[tid] = -1e30f; lS[tid] = 0.f; }

  f32x4 acc[2][4];
  #pragma unroll
  for (int mi = 0; mi < 2; ++mi)
    #pragma unroll
    for (int ni = 0; ni < 4; ++ni)
      acc[mi][ni] = (f32x4){0.f, 0.f, 0.f, 0.f};

  // ---- prologue DMA: tile 0 -> buf 0 (transposed layout, src-swizzled) ----
  #pragma unroll
  for (int c = 0; c < 8; ++c) {
    int drow = wid * 64 + c * 8 + (lane >> 3);
    int chunk = (lane & 7) ^ ((lane >> 3) & 7);
    const unsigned short* src = Tb + (size_t)drow * NSEQ + chunk * 8;
    unsigned short* dst = (unsigned short*)&Bt[0][(wid * 64 + c * 8) * KVBLK];
    __builtin_amdgcn_global_load_lds(
        (const __attribute__((address_space(1))) void*)src,
        (__attribute__((address_space(3))) void*)dst, 16, 0, 0);
  }

  for (int kt = 0; kt < NT; ++kt) {
    const int cur = kt & 1;

    asm volatile("s_waitcnt vmcnt(0)" ::: "memory");  // DMA(kt) + kf(kt) landed
    __builtin_amdgcn_s_barrier();                     // prev PV reads of buf cur^1 done

    if (kt + 1 < NT) {
      #pragma unroll
      for (int c = 0; c < 8; ++c) {
        int drow = wid * 64 + c * 8 + (lane >> 3);
        int chunk = (lane & 7) ^ ((lane >> 3) & 7);
        const unsigned short* src = Tb + (size_t)drow * NSEQ + (kt + 1) * KVBLK + chunk * 8;
        unsigned short* dst = (unsigned short*)&Bt[cur ^ 1][(wid * 64 + c * 8) * KVBLK];
        __builtin_amdgcn_global_load_lds(
            (const __attribute__((address_space(1))) void*)src,
            (__attribute__((address_space(3))) void*)dst, 16, 0, 0);
      }
    }

    // ---- QK^T from registers (2 independent chains) ----
    {
      f32x4 s0 = {0.f, 0.f, 0.f, 0.f};
      f32x4 s1 = {0.f, 0.f, 0.f, 0.f};
      __builtin_amdgcn_s_setprio(1);
      #pragma unroll
      for (int ks = 0; ks < 8; ++ks) {
        s0 = __builtin_amdgcn_mfma_f32_16x16x32_bf16(qf[2 * ks],     kf[2 * ks],     s0, 0, 0, 0);
        s1 = __builtin_amdgcn_mfma_f32_16x16x32_bf16(qf[2 * ks + 1], kf[2 * ks + 1], s1, 0, 0, 0);
      }
      __builtin_amdgcn_s_setprio(0);
      #pragma unroll
      for (int r = 0; r < 4; ++r)
        Ss[(qi * 16 + g4 * 4 + r) * SROWP + ki * 16 + l16] = s0[r] + s1[r];
    }
    asm volatile("s_waitcnt lgkmcnt(0)" ::: "memory");
    __builtin_amdgcn_s_barrier();

    // ---- online softmax: wave w owns rows 4w..4w+3 ----
    {
      int row = wid * 4 + g4;
      float sv[4];
      float mloc = -1e30f;
      #pragma unroll
      for (int j = 0; j < 4; ++j) {
        sv[j] = Ss[row * SROWP + l16 + 16 * j];
        mloc = fmaxf(mloc, sv[j]);
      }
      #pragma unroll
      for (int off = 1; off < 16; off <<= 1)
        mloc = fmaxf(mloc, __shfl_xor(mloc, off));
      float mold = mS[row];
      float mnew = fmaxf(mold, mloc);
      float al = __expf(mold - mnew);
      float psum = 0.f;
      #pragma unroll
      for (int j = 0; j < 4; ++j) {
        float p = __expf(sv[j] - mnew);
        psum += p;
        Ps[row * PROWP + l16 + 16 * j] = f2b(p);
      }
      #pragma unroll
      for (int off = 1; off < 16; off <<= 1)
        psum += __shfl_xor(psum, off);
      if (l16 == 0) {
        mS[row] = mnew;
        lS[row] = lS[row] * al + psum;
        aS[row] = al;
      }
    }
    asm volatile("s_waitcnt lgkmcnt(0)" ::: "memory");
    __builtin_amdgcn_s_barrier();

    // ---- K prefetch for next tile (lands during PV) ----
    if (kt + 1 < NT) {
      kptr += (size_t)KVBLK * D;
      #pragma unroll
      for (int ks = 0; ks < 16; ++ks)
        kf[ks] = *reinterpret_cast<const bf16x8*>(kptr + ks * 32);
    }

    // ---- rescale + PV: O^T += V^T * P^T  (wave owns d-slice [wid*64,+64)) ----
    {
      float al0 = aS[l16];
      float al1 = aS[16 + l16];
      #pragma unroll
      for (int ni = 0; ni < 4; ++ni)
        #pragma unroll
        for (int r = 0; r < 4; ++r) {
          acc[0][ni][r] *= al0;
          acc[1][ni][r] *= al1;
        }

      const char* Bc = (const char*)&Bt[cur][0];
      __builtin_amdgcn_s_setprio(1);
      #pragma unroll
      for (int ks = 0; ks < 2; ++ks) {
        const bf16x8 pf0 = *reinterpret_cast<const bf16x8*>(
            &Ps[l16 * PROWP + ks * 32 + g4 * 8]);
        const bf16x8 pf1 = *reinterpret_cast<const bf16x8*>(
            &Ps[(16 + l16) * PROWP + ks * 32 + g4 * 8]);
        #pragma unroll
        for (int ni = 0; ni < 4; ++ni) {
          int row = wid * 64 + ni * 16 + l16;
          int swz = (ks * 4 + g4) ^ (l16 & 7);
          const bf16x8 vf = *reinterpret_cast<const bf16x8*>(Bc + row * 128 + swz * 16);
          acc[0][ni] = __builtin_amdgcn_mfma_f32_16x16x32_bf16(vf, pf0, acc[0][ni], 0, 0, 0);
          acc[1][ni] = __builtin_amdgcn_mfma_f32_16x16x32_bf16(vf, pf1, acc[1][ni], 0, 0, 0);
        }
      }
      __builtin_amdgcn_s_setprio(0);
    }
  }

  // ---- epilogue: Out[q][d] = accT/l + A[q][d], d-contiguous float4 ----
  {
    float rl0 = 1.0f / lS[l16];
    float rl1 = 1.0f / lS[16 + l16];
    #pragma unroll
    for (int mi = 0; mi < 2; ++mi) {
      float rl = mi ? rl1 : rl0;
      int q = qbase + mi * 16 + l16;
      #pragma unroll
      for (int ni = 0; ni < 4; ++ni) {
        int d = wid * 64 + ni * 16 + g4 * 4;
        const float4 av = *reinterpret_cast<const float4*>(Ab + (size_t)q * D + d);
        float4 o;
        o.x = acc[mi][ni][0] * rl + av.x;
        o.y = acc[mi][ni][1] * rl + av.y;
        o.z = acc[mi][ni][2] * rl + av.z;
        o.w = acc[mi][ni][3] * rl + av.w;
        *reinterpret_cast<float4*>(Ob + (size_t)q * D + d) = o;
      }
    }
  }
}

// ------------------- round-3 kernel kept as ws fallback ---------------------
template<bool PRE>
__global__ __launch_bounds__(NTHREADS, 2)
void attn_fused(const float* __restrict__ A, const float* __restrict__ B32,
                const unsigned short* __restrict__ B16, float* __restrict__ Out) {
  __shared__ __align__(16) unsigned short Bs[2][BUFE];
  __shared__ float Ss[QBLK * SROWP];
  __shared__ unsigned short Ps[QBLK * PROWP];
  __shared__ float mS[QBLK];
  __shared__ float lS[QBLK];
  __shared__ float aS[QBLK];

  const int tid  = threadIdx.x;
  const int wid  = tid >> 6;
  const int lane = tid & 63;
  const int l16  = lane & 15;
  const int g4   = lane >> 4;

  const int batch = blockIdx.x & 7;
  const int qt    = blockIdx.x >> 3;
  const int qbase = qt * QBLK;

  const float*          Ab   = A   + (size_t)batch * NSEQ * D;
  const float*          Bb32 = B32 + (size_t)batch * NSEQ * D;
  const unsigned short* Bb16 = PRE ? (B16 + (size_t)batch * NSEQ * D) : nullptr;
  float*                Ob   = Out + (size_t)batch * NSEQ * D;

  const float scale = 0.04419417382415922f;

  const int qi = wid >> 2;
  const int ki = wid & 3;

  const int qrow = qbase + qi * 16 + l16;
  const float* Arow = Ab + (size_t)qrow * D;
  bf16x8 qf[16];
  #pragma unroll
  for (int ks = 0; ks < 16; ++ks) {
    int d0 = ks * 32 + g4 * 8;
    float4 v0 = *reinterpret_cast<const float4*>(Arow + d0);
    float4 v1 = *reinterpret_cast<const float4*>(Arow + d0 + 4);
    bf16x8 f;
    f[0] = (short)f2b(v0.x * scale); f[1] = (short)f2b(v0.y * scale);
    f[2] = (short)f2b(v0.z * scale); f[3] = (short)f2b(v0.w * scale);
    f[4] = (short)f2b(v1.x * scale); f[5] = (short)f2b(v1.y * scale);
    f[6] = (short)f2b(v1.z * scale); f[7] = (short)f2b(v1.w * scale);
    qf[ks] = f;
  }
  if (tid < QBLK) { mS[tid] = -1e30f; lS[tid] = 0.f; }

  f32x4 acc[2][4];
  #pragma unroll
  for (int mi = 0; mi < 2; ++mi)
    #pragma unroll
    for (int ni = 0; ni < 4; ++ni)
      acc[mi][ni] = (f32x4){0.f, 0.f, 0.f, 0.f};

  if constexpr (PRE) {
    #pragma unroll
    for (int c = 0; c < 8; ++c) {
      int id = wid * 8 + c;
      int g = id >> 2, q = id & 3;
      const unsigned short* src = Bb16
          + (size_t)(g * 4 + ((lane >> 1) & 3)) * D
          + q * 128 + (lane >> 3) * 16 + (lane & 1) * 8;
      unsigned short* dst = &Bs[0][g * ROWE + q * 512];
      __builtin_amdgcn_global_load_lds(
          (const __attribute__((address_space(1))) void*)src,
          (__attribute__((address_space(3))) void*)dst, 16, 0, 0);
    }
  }

  for (int kt = 0; kt < NT; ++kt) {
    const int cur = PRE ? (kt & 1) : 0;

    if constexpr (PRE) {
      asm volatile("s_waitcnt vmcnt(0)" ::: "memory");
      __builtin_amdgcn_s_barrier();
      if (kt + 1 < NT) {
        const unsigned short* Bt = Bb16 + (size_t)(kt + 1) * KVBLK * D;
        #pragma unroll
        for (int c = 0; c < 8; ++c) {
          int id = wid * 8 + c;
          int g = id >> 2, q = id & 3;
          const unsigned short* src = Bt
              + (size_t)(g * 4 + ((lane >> 1) & 3)) * D
              + q * 128 + (lane >> 3) * 16 + (lane & 1) * 8;
          unsigned short* dst = &Bs[cur ^ 1][g * ROWE + q * 512];
          __builtin_amdgcn_global_load_lds(
              (const __attribute__((address_space(1))) void*)src,
              (__attribute__((address_space(3))) void*)dst, 16, 0, 0);
        }
      }
    } else {
      __builtin_amdgcn_s_barrier();
      const float* Bt = Bb32 + (size_t)kt * KVBLK * D;
      #pragma unroll
      for (int c = 0; c < 8; ++c) {
        int id = wid * 8 + c;
        int g = id >> 2, q = id & 3;
        int kv = g * 4 + ((lane >> 1) & 3);
        int d  = q * 128 + (lane >> 3) * 16 + (lane & 1) * 8;
        const float* s = Bt + (size_t)kv * D + d;
        float4 v0 = *reinterpret_cast<const float4*>(s);
        float4 v1 = *reinterpret_cast<const float4*>(s + 4);
        bf16x8 h;
        h[0] = (short)f2b(v0.x); h[1] = (short)f2b(v0.y);
        h[2] = (short)f2b(v0.z); h[3] = (short)f2b(v0.w);
        h[4] = (short)f2b(v1.x); h[5] = (short)f2b(v1.y);
        h[6] = (short)f2b(v1.z); h[7] = (short)f2b(v1.w);
        *reinterpret_cast<bf16x8*>(&Bs[0][g * ROWE + q * 512 + lane * 8]) = h;
      }
      asm volatile("s_waitcnt lgkmcnt(0)" ::: "memory");
      __builtin_amdgcn_s_barrier();
    }

    {
      f32x4 s = {0.f, 0.f, 0.f, 0.f};
      const int bbase = (ki * 4 + (l16 >> 2)) * ROWE + (l16 & 3) * 16 + (g4 & 1) * 8;
      __builtin_amdgcn_s_setprio(1);
      #pragma unroll
      for (int ks = 0; ks < 16; ++ks) {
        const bf16x8 bf = *reinterpret_cast<const bf16x8*>(
            &Bs[cur][bbase + (ks * 2 + (g4 >> 1)) * 64]);
        s = __builtin_amdgcn_mfma_f32_16x16x32_bf16(qf[ks], bf, s, 0, 0, 0);
      }
      __builtin_amdgcn_s_setprio(0);
      #pragma unroll
      for (int r = 0; r < 4; ++r)
        Ss[(qi * 16 + g4 * 4 + r) * SROWP + ki * 16 + l16] = s[r];
    }
    asm volatile("s_waitcnt lgkmcnt(0)" ::: "memory");
    __builtin_amdgcn_s_barrier();

    {
      int row = wid * 4 + g4;
      float sv[4];
      float mloc = -1e30f;
      #pragma unroll
      for (int j = 0; j < 4; ++j) {
        sv[j] = Ss[row * SROWP + l16 + 16 * j];
        mloc = fmaxf(mloc, sv[j]);
      }
      #pragma unroll
      for (int off = 1; off < 16; off <<= 1)
        mloc = fmaxf(mloc, __shfl_xor(mloc, off));
      float mold = mS[row];
      float mnew = fmaxf(mold, mloc);
      float al = __expf(mold - mnew);
      float psum = 0.f;
      #pragma unroll
      for (int j = 0; j < 4; ++j) {
        float p = __expf(sv[j] - mnew);
        psum += p;
        Ps[row * PROWP + l16 + 16 * j] = f2b(p);
      }
      #pragma unroll
      for (int off = 1; off < 16; off <<= 1)
        psum += __shfl_xor(psum, off);
      if (l16 == 0) {
        mS[row] = mnew;
        lS[row] = lS[row] * al + psum;
        aS[row] = al;
      }
    }
    asm volatile("s_waitcnt lgkmcnt(0)" ::: "memory");
    __builtin_amdgcn_s_barrier();

    {
      float alv[2][4];
      #pragma unroll
      for (int mi = 0; mi < 2; ++mi)
        #pragma unroll
        for (int r = 0; r < 4; ++r)
          alv[mi][r] = aS[mi * 16 + g4 * 4 + r];
      #pragma unroll
      for (int mi = 0; mi < 2; ++mi)
        #pragma unroll
        for (int ni = 0; ni < 4; ++ni)
          #pragma unroll
          for (int r = 0; r < 4; ++r)
            acc[mi][ni][r] *= alv[mi][r];

      const unsigned short* Bc = &Bs[cur][0];
      __builtin_amdgcn_s_setprio(1);
      #pragma unroll
      for (int ks = 0; ks < 2; ++ks) {
        bf16x8 pf[2];
        #pragma unroll
        for (int mi = 0; mi < 2; ++mi)
          pf[mi] = *reinterpret_cast<const bf16x8*>(
              &Ps[(mi * 16 + l16) * PROWP + ks * 32 + g4 * 8]);
        #pragma unroll
        for (int ni = 0; ni < 4; ++ni) {
          bf16x8 vv;
          #pragma unroll
          for (int j = 0; j < 8; ++j)
            vv[j] = (short)Bc[(ks * 8 + g4 * 2 + (j >> 2)) * ROWE
                              + (wid * 4 + ni) * 64 + (j & 3) * 16 + l16];
          #pragma unroll
          for (int mi = 0; mi < 2; ++mi)
            acc[mi][ni] = __builtin_amdgcn_mfma_f32_16x16x32_bf16(pf[mi], vv, acc[mi][ni], 0, 0, 0);
        }
      }
      __builtin_amdgcn_s_setprio(0);
    }
  }

  float rl[2][4];
  #pragma unroll
  for (int mi = 0; mi < 2; ++mi)
    #pragma unroll
    for (int r = 0; r < 4; ++r)
      rl[mi][r] = 1.0f / lS[mi * 16 + g4 * 4 + r];
  #pragma unroll
  for (int mi = 0; mi < 2; ++mi)
    #pragma unroll
    for (int ni = 0; ni < 4; ++ni)
      #pragma unroll
      for (int r = 0; r < 4; ++r) {
        int q = qbase + mi * 16 + g4 * 4 + r;
        int d = wid * 64 + ni * 16 + l16;
        size_t off = (size_t)q * D + d;
        Ob[off] = acc[mi][ni][r] * rl[mi][r] + Ab[off];
      }
}

extern "C" void kernel_launch(void* const* d_in, const int* in_sizes, int n_in,
                              void* d_out, int out_size, void* d_ws, size_t ws_size,
                              hipStream_t stream) {
  const float* a = (const float*)d_in[0];
  const float* b = (const float*)d_in[1];
  float* out = (float*)d_out;
  const size_t one = (size_t)NB * NSEQ * D * sizeof(unsigned short);  // 16 MB
  dim3 grid(NB * (NSEQ / QBLK));
  dim3 block(NTHREADS);
  if (ws_size >= 2 * one) {
    unsigned short* b16 = (unsigned short*)d_ws;
    unsigned short* bT  = b16 + (size_t)NB * NSEQ * D;
    conv_dual<<<NB * 256, 256, 0, stream>>>(b, b16, bT);
    attn_v5<<<grid, block, 0, stream>>>(a, b16, bT, out);
  } else if (ws_size >= one) {
    unsigned short* b16 = (unsigned short*)d_ws;
    conv_b16<<<4096, 256, 0, stream>>>(b, b16);
    attn_fused<true><<<grid, block, 0, stream>>>(a, b, b16, out);
  } else {
    attn_fused<false><<<grid, block, 0, stream>>>(a, b, nullptr, out);
  }
}

// Round 6
// 358.751 us; speedup vs baseline: 1.0552x; 1.0552x over previous
//
#include <hip/hip_runtime.h>
#include <hip/hip_bf16.h>

#define D 512
#define NSEQ 2048
#define NB 8
#define QBLK 32
#define KVBLK 64
#define NTHREADS 512
#define NT (NSEQ / KVBLK)          // 32 kv tiles
#define ROWE 2056                  // subtiled layout: elems per 4-row group
#define BUFE (16 * ROWE)
#define SROWP (KVBLK + 4)          // f32 row for Ss
#define PROWP (KVBLK + 8)          // bf16 row for Ps
#define CROWP 68                   // conv transpose tile stride (u16)

typedef __attribute__((ext_vector_type(8))) short bf16x8;
typedef __attribute__((ext_vector_type(4))) float f32x4;
typedef __attribute__((ext_vector_type(4))) unsigned short u16x4;

static __device__ __forceinline__ unsigned short f2b(float f) {
  unsigned u = __builtin_bit_cast(unsigned, f);
  return (unsigned short)((u + 0x7FFFu + ((u >> 16) & 1u)) >> 16);
}

// ---------------- conv: fp32 B -> b16 [kv][d] (memory-bound) ----------------
__global__ __launch_bounds__(256) void conv_b16(const float* __restrict__ in,
                                                unsigned short* __restrict__ out) {
  size_t i = ((size_t)blockIdx.x * 256 + threadIdx.x) * 8;
  float4 v0 = *reinterpret_cast<const float4*>(in + i);
  float4 v1 = *reinterpret_cast<const float4*>(in + i + 4);
  bf16x8 h;
  h[0] = (short)f2b(v0.x); h[1] = (short)f2b(v0.y);
  h[2] = (short)f2b(v0.z); h[3] = (short)f2b(v0.w);
  h[4] = (short)f2b(v1.x); h[5] = (short)f2b(v1.y);
  h[6] = (short)f2b(v1.z); h[7] = (short)f2b(v1.w);
  *reinterpret_cast<bf16x8*>(out + i) = h;
}

// ------- conv: fp32 B -> b16 [kv][d] AND b16T [d][kv] (64x64 LDS tiles) -----
__global__ __launch_bounds__(256) void conv_dual(const float* __restrict__ in,
                                                 unsigned short* __restrict__ b16,
                                                 unsigned short* __restrict__ bT) {
  __shared__ unsigned short tile[64 * CROWP];
  const int bid = blockIdx.x;
  const int batch = bid >> 8;
  const int rem = bid & 255;
  const int kvt = rem >> 3;      // 0..31
  const int dt  = rem & 7;       // 0..7
  const int t = threadIdx.x;
  const int r = t >> 2;          // 0..63 (kv row in tile)
  const int c = (t & 3) * 16;    // d col in tile

  const float* src = in + ((size_t)batch * NSEQ + kvt * 64 + r) * D + dt * 64 + c;
  unsigned short* o16 = b16 + ((size_t)batch * NSEQ + kvt * 64 + r) * D + dt * 64 + c;

  float4 v0 = *reinterpret_cast<const float4*>(src);
  float4 v1 = *reinterpret_cast<const float4*>(src + 4);
  float4 v2 = *reinterpret_cast<const float4*>(src + 8);
  float4 v3 = *reinterpret_cast<const float4*>(src + 12);
  bf16x8 h0, h1;
  h0[0] = (short)f2b(v0.x); h0[1] = (short)f2b(v0.y);
  h0[2] = (short)f2b(v0.z); h0[3] = (short)f2b(v0.w);
  h0[4] = (short)f2b(v1.x); h0[5] = (short)f2b(v1.y);
  h0[6] = (short)f2b(v1.z); h0[7] = (short)f2b(v1.w);
  h1[0] = (short)f2b(v2.x); h1[1] = (short)f2b(v2.y);
  h1[2] = (short)f2b(v2.z); h1[3] = (short)f2b(v2.w);
  h1[4] = (short)f2b(v3.x); h1[5] = (short)f2b(v3.y);
  h1[6] = (short)f2b(v3.z); h1[7] = (short)f2b(v3.w);
  *reinterpret_cast<bf16x8*>(o16)     = h0;
  *reinterpret_cast<bf16x8*>(o16 + 8) = h1;
  #pragma unroll
  for (int i = 0; i < 4; ++i) {
    u16x4 w;
    w[0] = (unsigned short)((i < 2 ? h0 : h1)[(i & 1) * 4 + 0]);
    w[1] = (unsigned short)((i < 2 ? h0 : h1)[(i & 1) * 4 + 1]);
    w[2] = (unsigned short)((i < 2 ? h0 : h1)[(i & 1) * 4 + 2]);
    w[3] = (unsigned short)((i < 2 ? h0 : h1)[(i & 1) * 4 + 3]);
    *reinterpret_cast<u16x4*>(&tile[r * CROWP + c + i * 4]) = w;
  }
  __syncthreads();

  // phase 2: wave w owns kv chunk w*16..+15; lane dr = d row 0..63
  const int w  = t >> 6;
  const int dr = t & 63;
  unsigned short* oT = bT + (size_t)batch * D * NSEQ
                          + (size_t)(dt * 64 + dr) * NSEQ + kvt * 64 + w * 16;
  unsigned short g[16];
  #pragma unroll
  for (int i = 0; i < 16; ++i)
    g[i] = tile[(w * 16 + i) * CROWP + dr];
  bf16x8 p0, p1;
  #pragma unroll
  for (int i = 0; i < 8; ++i) { p0[i] = (short)g[i]; p1[i] = (short)g[8 + i]; }
  *reinterpret_cast<bf16x8*>(oT)     = p0;
  *reinterpret_cast<bf16x8*>(oT + 8) = p1;
}

// ---------------------------- v6 main kernel --------------------------------
// Register budget is the binding constraint (r4/r5: qf+kf+acc = 160+ regs vs
// compiler-pinned 128 -> 60-reg spill, 375us with both pipes idle). v6 keeps
// ONLY kf[16] (64 VGPR) in registers; Q lives in LDS (subtiled r3 layout,
// proven conflict-free b128 reads). Bt (V^T, [d][kv], src-XOR-swizzled) is
// single-buffered: QK^T never touches it, so DMA(kt) issued at loop top hides
// under QK^T+softmax and drains once before PV. 3 barriers/tile.
// LDS: Qs 32.9K + Bt 64K + Ss 8.7K + Ps 4.6K + stats = ~112.6 KB.
__global__ __launch_bounds__(NTHREADS, 1)
void attn_v6(const float* __restrict__ A, const unsigned short* __restrict__ K16,
             const unsigned short* __restrict__ T16, float* __restrict__ Out) {
  __shared__ __align__(16) unsigned short Qs[8 * ROWE];      // 32896 B
  __shared__ __align__(16) unsigned short Bt[D * KVBLK];     // 65536 B
  __shared__ float Ss[QBLK * SROWP];
  __shared__ unsigned short Ps[QBLK * PROWP];
  __shared__ float mS[QBLK];
  __shared__ float lS[QBLK];
  __shared__ float aS[QBLK];

  const int tid  = threadIdx.x;
  const int wid  = tid >> 6;
  const int lane = tid & 63;
  const int l16  = lane & 15;
  const int g4   = lane >> 4;

  const int batch = blockIdx.x & 7;       // batch -> XCD (L2 locality for b panel)
  const int qt    = blockIdx.x >> 3;
  const int qbase = qt * QBLK;

  const float*          Ab = A   + (size_t)batch * NSEQ * D;
  const unsigned short* Kb = K16 + (size_t)batch * NSEQ * D;
  const unsigned short* Tb = T16 + (size_t)batch * D * NSEQ;
  float*                Ob = Out + (size_t)batch * NSEQ * D;

  const float scale = 0.04419417382415922f;  // 1/sqrt(512)

  const int qi = wid >> 2;   // q 16-tile for QK^T
  const int ki = wid & 3;    // kv 16-tile for QK^T

  // ---- stage Q into LDS (pre-scaled), subtiled layout ----
  // thread t: q = t>>4, d-chunk = (t&15)*32 .. +31
  {
    const int q  = tid >> 4;
    const int dc = (tid & 15) * 32;
    const float* src = Ab + (size_t)(qbase + q) * D + dc;
    const int gbase = (q >> 2) * ROWE + (q & 3) * 16;
    #pragma unroll
    for (int j = 0; j < 4; ++j) {
      float4 v0 = *reinterpret_cast<const float4*>(src + j * 8);
      float4 v1 = *reinterpret_cast<const float4*>(src + j * 8 + 4);
      bf16x8 h;
      h[0] = (short)f2b(v0.x * scale); h[1] = (short)f2b(v0.y * scale);
      h[2] = (short)f2b(v0.z * scale); h[3] = (short)f2b(v0.w * scale);
      h[4] = (short)f2b(v1.x * scale); h[5] = (short)f2b(v1.y * scale);
      h[6] = (short)f2b(v1.z * scale); h[7] = (short)f2b(v1.w * scale);
      int d = dc + j * 8;
      *reinterpret_cast<bf16x8*>(&Qs[gbase + (d >> 4) * 64 + (d & 15)]) = h;
    }
  }
  if (tid < QBLK) { mS[tid] = -1e30f; lS[tid] = 0.f; }

  f32x4 acc[2][4];
  #pragma unroll
  for (int mi = 0; mi < 2; ++mi)
    #pragma unroll
    for (int ni = 0; ni < 4; ++ni)
      acc[mi][ni] = (f32x4){0.f, 0.f, 0.f, 0.f};

  asm volatile("s_waitcnt lgkmcnt(0)" ::: "memory");
  __builtin_amdgcn_s_barrier();     // Qs + stats visible

  // ---- kf tile 0 (from b16 [kv][d]) ----
  const unsigned short* kptr = Kb + (size_t)(ki * 16 + l16) * D + g4 * 8;
  bf16x8 kf[16];
  #pragma unroll
  for (int ks = 0; ks < 16; ++ks)
    kf[ks] = *reinterpret_cast<const bf16x8*>(kptr + ks * 32);

  const int qread_base = (qi * 4 + (l16 >> 2)) * ROWE + (l16 & 3) * 16 + (g4 & 1) * 8;

  for (int kt = 0; kt < NT; ++kt) {
    // ---- barrier A: prev PV done reading Bt -> safe to overwrite ----
    if (kt > 0) {
      asm volatile("s_waitcnt lgkmcnt(0)" ::: "memory");
      __builtin_amdgcn_s_barrier();
    }
    // ---- issue DMA(kt): V^T tile -> Bt (src-XOR-swizzled, linear dest) ----
    {
      #pragma unroll
      for (int c = 0; c < 8; ++c) {
        int drow = wid * 64 + c * 8 + (lane >> 3);
        int chunk = (lane & 7) ^ ((lane >> 3) & 7);
        const unsigned short* src = Tb + (size_t)drow * NSEQ + kt * KVBLK + chunk * 8;
        unsigned short* dst = (unsigned short*)&Bt[(wid * 64 + c * 8) * KVBLK];
        __builtin_amdgcn_global_load_lds(
            (const __attribute__((address_space(1))) void*)src,
            (__attribute__((address_space(3))) void*)dst, 16, 0, 0);
      }
    }

    // ---- QK^T: Q-frag from Qs (b128), K from kf regs ----
    {
      f32x4 s0 = {0.f, 0.f, 0.f, 0.f};
      f32x4 s1 = {0.f, 0.f, 0.f, 0.f};
      __builtin_amdgcn_s_setprio(1);
      #pragma unroll
      for (int ks = 0; ks < 8; ++ks) {
        const bf16x8 q0 = *reinterpret_cast<const bf16x8*>(
            &Qs[qread_base + ((2 * ks) * 2 + (g4 >> 1)) * 64]);
        const bf16x8 q1 = *reinterpret_cast<const bf16x8*>(
            &Qs[qread_base + ((2 * ks + 1) * 2 + (g4 >> 1)) * 64]);
        s0 = __builtin_amdgcn_mfma_f32_16x16x32_bf16(q0, kf[2 * ks],     s0, 0, 0, 0);
        s1 = __builtin_amdgcn_mfma_f32_16x16x32_bf16(q1, kf[2 * ks + 1], s1, 0, 0, 0);
      }
      __builtin_amdgcn_s_setprio(0);
      #pragma unroll
      for (int r = 0; r < 4; ++r)
        Ss[(qi * 16 + g4 * 4 + r) * SROWP + ki * 16 + l16] = s0[r] + s1[r];
    }

    // ---- kf prefetch for tile kt+1 (lands during softmax; drained pre-PV) ----
    if (kt + 1 < NT) {
      kptr += (size_t)KVBLK * D;
      #pragma unroll
      for (int ks = 0; ks < 16; ++ks)
        kf[ks] = *reinterpret_cast<const bf16x8*>(kptr + ks * 32);
    }

    asm volatile("s_waitcnt lgkmcnt(0)" ::: "memory");
    __builtin_amdgcn_s_barrier();   // barrier B: Ss visible

    // ---- online softmax: wave w owns rows 4w..4w+3 ----
    {
      int row = wid * 4 + g4;
      float sv[4];
      float mloc = -1e30f;
      #pragma unroll
      for (int j = 0; j < 4; ++j) {
        sv[j] = Ss[row * SROWP + l16 + 16 * j];
        mloc = fmaxf(mloc, sv[j]);
      }
      #pragma unroll
      for (int off = 1; off < 16; off <<= 1)
        mloc = fmaxf(mloc, __shfl_xor(mloc, off));
      float mold = mS[row];
      float mnew = fmaxf(mold, mloc);
      float al = __expf(mold - mnew);
      float psum = 0.f;
      #pragma unroll
      for (int j = 0; j < 4; ++j) {
        float p = __expf(sv[j] - mnew);
        psum += p;
        Ps[row * PROWP + l16 + 16 * j] = f2b(p);
      }
      #pragma unroll
      for (int off = 1; off < 16; off <<= 1)
        psum += __shfl_xor(psum, off);
      if (l16 == 0) {
        mS[row] = mnew;
        lS[row] = lS[row] * al + psum;
        aS[row] = al;
      }
    }

    // ---- drain DMA (+ kf prefetch) and publish Ps ----
    asm volatile("s_waitcnt vmcnt(0)" ::: "memory");
    asm volatile("s_waitcnt lgkmcnt(0)" ::: "memory");
    __builtin_amdgcn_s_barrier();   // barrier C: Ps + Bt ready

    // ---- rescale + PV: O^T += V^T * P^T  (wave owns d-slice [wid*64,+64)) ----
    {
      float al0 = aS[l16];
      float al1 = aS[16 + l16];
      #pragma unroll
      for (int ni = 0; ni < 4; ++ni)
        #pragma unroll
        for (int r = 0; r < 4; ++r) {
          acc[0][ni][r] *= al0;
          acc[1][ni][r] *= al1;
        }

      const char* Bc = (const char*)&Bt[0];
      __builtin_amdgcn_s_setprio(1);
      #pragma unroll
      for (int ks = 0; ks < 2; ++ks) {
        const bf16x8 pf0 = *reinterpret_cast<const bf16x8*>(
            &Ps[l16 * PROWP + ks * 32 + g4 * 8]);
        const bf16x8 pf1 = *reinterpret_cast<const bf16x8*>(
            &Ps[(16 + l16) * PROWP + ks * 32 + g4 * 8]);
        #pragma unroll
        for (int ni = 0; ni < 4; ++ni) {
          int row = wid * 64 + ni * 16 + l16;
          int swz = (ks * 4 + g4) ^ (l16 & 7);
          const bf16x8 vf = *reinterpret_cast<const bf16x8*>(Bc + row * 128 + swz * 16);
          acc[0][ni] = __builtin_amdgcn_mfma_f32_16x16x32_bf16(vf, pf0, acc[0][ni], 0, 0, 0);
          acc[1][ni] = __builtin_amdgcn_mfma_f32_16x16x32_bf16(vf, pf1, acc[1][ni], 0, 0, 0);
        }
      }
      __builtin_amdgcn_s_setprio(0);
    }
  }

  // ---- epilogue: Out[q][d] = accT/l + A[q][d], d-contiguous float4 ----
  {
    float rl0 = 1.0f / lS[l16];
    float rl1 = 1.0f / lS[16 + l16];
    #pragma unroll
    for (int mi = 0; mi < 2; ++mi) {
      float rl = mi ? rl1 : rl0;
      int q = qbase + mi * 16 + l16;
      #pragma unroll
      for (int ni = 0; ni < 4; ++ni) {
        int d = wid * 64 + ni * 16 + g4 * 4;
        const float4 av = *reinterpret_cast<const float4*>(Ab + (size_t)q * D + d);
        float4 o;
        o.x = acc[mi][ni][0] * rl + av.x;
        o.y = acc[mi][ni][1] * rl + av.y;
        o.z = acc[mi][ni][2] * rl + av.z;
        o.w = acc[mi][ni][3] * rl + av.w;
        *reinterpret_cast<float4*>(Ob + (size_t)q * D + d) = o;
      }
    }
  }
}

// ------------------- round-3 kernel kept as ws fallback ---------------------
template<bool PRE>
__global__ __launch_bounds__(NTHREADS, 2)
void attn_fused(const float* __restrict__ A, const float* __restrict__ B32,
                const unsigned short* __restrict__ B16, float* __restrict__ Out) {
  __shared__ __align__(16) unsigned short Bs[2][BUFE];
  __shared__ float Ss[QBLK * SROWP];
  __shared__ unsigned short Ps[QBLK * PROWP];
  __shared__ float mS[QBLK];
  __shared__ float lS[QBLK];
  __shared__ float aS[QBLK];

  const int tid  = threadIdx.x;
  const int wid  = tid >> 6;
  const int lane = tid & 63;
  const int l16  = lane & 15;
  const int g4   = lane >> 4;

  const int batch = blockIdx.x & 7;
  const int qt    = blockIdx.x >> 3;
  const int qbase = qt * QBLK;

  const float*          Ab   = A   + (size_t)batch * NSEQ * D;
  const float*          Bb32 = B32 + (size_t)batch * NSEQ * D;
  const unsigned short* Bb16 = PRE ? (B16 + (size_t)batch * NSEQ * D) : nullptr;
  float*                Ob   = Out + (size_t)batch * NSEQ * D;

  const float scale = 0.04419417382415922f;

  const int qi = wid >> 2;
  const int ki = wid & 3;

  const int qrow = qbase + qi * 16 + l16;
  const float* Arow = Ab + (size_t)qrow * D;
  bf16x8 qf[16];
  #pragma unroll
  for (int ks = 0; ks < 16; ++ks) {
    int d0 = ks * 32 + g4 * 8;
    float4 v0 = *reinterpret_cast<const float4*>(Arow + d0);
    float4 v1 = *reinterpret_cast<const float4*>(Arow + d0 + 4);
    bf16x8 f;
    f[0] = (short)f2b(v0.x * scale); f[1] = (short)f2b(v0.y * scale);
    f[2] = (short)f2b(v0.z * scale); f[3] = (short)f2b(v0.w * scale);
    f[4] = (short)f2b(v1.x * scale); f[5] = (short)f2b(v1.y * scale);
    f[6] = (short)f2b(v1.z * scale); f[7] = (short)f2b(v1.w * scale);
    qf[ks] = f;
  }
  if (tid < QBLK) { mS[tid] = -1e30f; lS[tid] = 0.f; }

  f32x4 acc[2][4];
  #pragma unroll
  for (int mi = 0; mi < 2; ++mi)
    #pragma unroll
    for (int ni = 0; ni < 4; ++ni)
      acc[mi][ni] = (f32x4){0.f, 0.f, 0.f, 0.f};

  if constexpr (PRE) {
    #pragma unroll
    for (int c = 0; c < 8; ++c) {
      int id = wid * 8 + c;
      int g = id >> 2, q = id & 3;
      const unsigned short* src = Bb16
          + (size_t)(g * 4 + ((lane >> 1) & 3)) * D
          + q * 128 + (lane >> 3) * 16 + (lane & 1) * 8;
      unsigned short* dst = &Bs[0][g * ROWE + q * 512];
      __builtin_amdgcn_global_load_lds(
          (const __attribute__((address_space(1))) void*)src,
          (__attribute__((address_space(3))) void*)dst, 16, 0, 0);
    }
  }

  for (int kt = 0; kt < NT; ++kt) {
    const int cur = PRE ? (kt & 1) : 0;

    if constexpr (PRE) {
      asm volatile("s_waitcnt vmcnt(0)" ::: "memory");
      __builtin_amdgcn_s_barrier();
      if (kt + 1 < NT) {
        const unsigned short* Bt2 = Bb16 + (size_t)(kt + 1) * KVBLK * D;
        #pragma unroll
        for (int c = 0; c < 8; ++c) {
          int id = wid * 8 + c;
          int g = id >> 2, q = id & 3;
          const unsigned short* src = Bt2
              + (size_t)(g * 4 + ((lane >> 1) & 3)) * D
              + q * 128 + (lane >> 3) * 16 + (lane & 1) * 8;
          unsigned short* dst = &Bs[cur ^ 1][g * ROWE + q * 512];
          __builtin_amdgcn_global_load_lds(
              (const __attribute__((address_space(1))) void*)src,
              (__attribute__((address_space(3))) void*)dst, 16, 0, 0);
        }
      }
    } else {
      __builtin_amdgcn_s_barrier();
      const float* Bt2 = Bb32 + (size_t)kt * KVBLK * D;
      #pragma unroll
      for (int c = 0; c < 8; ++c) {
        int id = wid * 8 + c;
        int g = id >> 2, q = id & 3;
        int kv = g * 4 + ((lane >> 1) & 3);
        int d  = q * 128 + (lane >> 3) * 16 + (lane & 1) * 8;
        const float* s = Bt2 + (size_t)kv * D + d;
        float4 v0 = *reinterpret_cast<const float4*>(s);
        float4 v1 = *reinterpret_cast<const float4*>(s + 4);
        bf16x8 h;
        h[0] = (short)f2b(v0.x); h[1] = (short)f2b(v0.y);
        h[2] = (short)f2b(v0.z); h[3] = (short)f2b(v0.w);
        h[4] = (short)f2b(v1.x); h[5] = (short)f2b(v1.y);
        h[6] = (short)f2b(v1.z); h[7] = (short)f2b(v1.w);
        *reinterpret_cast<bf16x8*>(&Bs[0][g * ROWE + q * 512 + lane * 8]) = h;
      }
      asm volatile("s_waitcnt lgkmcnt(0)" ::: "memory");
      __builtin_amdgcn_s_barrier();
    }

    {
      f32x4 s = {0.f, 0.f, 0.f, 0.f};
      const int bbase = (ki * 4 + (l16 >> 2)) * ROWE + (l16 & 3) * 16 + (g4 & 1) * 8;
      __builtin_amdgcn_s_setprio(1);
      #pragma unroll
      for (int ks = 0; ks < 16; ++ks) {
        const bf16x8 bf = *reinterpret_cast<const bf16x8*>(
            &Bs[cur][bbase + (ks * 2 + (g4 >> 1)) * 64]);
        s = __builtin_amdgcn_mfma_f32_16x16x32_bf16(qf[ks], bf, s, 0, 0, 0);
      }
      __builtin_amdgcn_s_setprio(0);
      #pragma unroll
      for (int r = 0; r < 4; ++r)
        Ss[(qi * 16 + g4 * 4 + r) * SROWP + ki * 16 + l16] = s[r];
    }
    asm volatile("s_waitcnt lgkmcnt(0)" ::: "memory");
    __builtin_amdgcn_s_barrier();

    {
      int row = wid * 4 + g4;
      float sv[4];
      float mloc = -1e30f;
      #pragma unroll
      for (int j = 0; j < 4; ++j) {
        sv[j] = Ss[row * SROWP + l16 + 16 * j];
        mloc = fmaxf(mloc, sv[j]);
      }
      #pragma unroll
      for (int off = 1; off < 16; off <<= 1)
        mloc = fmaxf(mloc, __shfl_xor(mloc, off));
      float mold = mS[row];
      float mnew = fmaxf(mold, mloc);
      float al = __expf(mold - mnew);
      float psum = 0.f;
      #pragma unroll
      for (int j = 0; j < 4; ++j) {
        float p = __expf(sv[j] - mnew);
        psum += p;
        Ps[row * PROWP + l16 + 16 * j] = f2b(p);
      }
      #pragma unroll
      for (int off = 1; off < 16; off <<= 1)
        psum += __shfl_xor(psum, off);
      if (l16 == 0) {
        mS[row] = mnew;
        lS[row] = lS[row] * al + psum;
        aS[row] = al;
      }
    }
    asm volatile("s_waitcnt lgkmcnt(0)" ::: "memory");
    __builtin_amdgcn_s_barrier();

    {
      float alv[2][4];
      #pragma unroll
      for (int mi = 0; mi < 2; ++mi)
        #pragma unroll
        for (int r = 0; r < 4; ++r)
          alv[mi][r] = aS[mi * 16 + g4 * 4 + r];
      #pragma unroll
      for (int mi = 0; mi < 2; ++mi)
        #pragma unroll
        for (int ni = 0; ni < 4; ++ni)
          #pragma unroll
          for (int r = 0; r < 4; ++r)
            acc[mi][ni][r] *= alv[mi][r];

      const unsigned short* Bc = &Bs[cur][0];
      __builtin_amdgcn_s_setprio(1);
      #pragma unroll
      for (int ks = 0; ks < 2; ++ks) {
        bf16x8 pf[2];
        #pragma unroll
        for (int mi = 0; mi < 2; ++mi)
          pf[mi] = *reinterpret_cast<const bf16x8*>(
              &Ps[(mi * 16 + l16) * PROWP + ks * 32 + g4 * 8]);
        #pragma unroll
        for (int ni = 0; ni < 4; ++ni) {
          bf16x8 vv;
          #pragma unroll
          for (int j = 0; j < 8; ++j)
            vv[j] = (short)Bc[(ks * 8 + g4 * 2 + (j >> 2)) * ROWE
                              + (wid * 4 + ni) * 64 + (j & 3) * 16 + l16];
          #pragma unroll
          for (int mi = 0; mi < 2; ++mi)
            acc[mi][ni] = __builtin_amdgcn_mfma_f32_16x16x32_bf16(pf[mi], vv, acc[mi][ni], 0, 0, 0);
        }
      }
      __builtin_amdgcn_s_setprio(0);
    }
  }

  float rl[2][4];
  #pragma unroll
  for (int mi = 0; mi < 2; ++mi)
    #pragma unroll
    for (int r = 0; r < 4; ++r)
      rl[mi][r] = 1.0f / lS[mi * 16 + g4 * 4 + r];
  #pragma unroll
  for (int mi = 0; mi < 2; ++mi)
    #pragma unroll
    for (int ni = 0; ni < 4; ++ni)
      #pragma unroll
      for (int r = 0; r < 4; ++r) {
        int q = qbase + mi * 16 + g4 * 4 + r;
        int d = wid * 64 + ni * 16 + l16;
        size_t off = (size_t)q * D + d;
        Ob[off] = acc[mi][ni][r] * rl[mi][r] + Ab[off];
      }
}

extern "C" void kernel_launch(void* const* d_in, const int* in_sizes, int n_in,
                              void* d_out, int out_size, void* d_ws, size_t ws_size,
                              hipStream_t stream) {
  const float* a = (const float*)d_in[0];
  const float* b = (const float*)d_in[1];
  float* out = (float*)d_out;
  const size_t one = (size_t)NB * NSEQ * D * sizeof(unsigned short);  // 16 MB
  dim3 grid(NB * (NSEQ / QBLK));
  dim3 block(NTHREADS);
  if (ws_size >= 2 * one) {
    unsigned short* b16 = (unsigned short*)d_ws;
    unsigned short* bT  = b16 + (size_t)NB * NSEQ * D;
    conv_dual<<<NB * 256, 256, 0, stream>>>(b, b16, bT);
    attn_v6<<<grid, block, 0, stream>>>(a, b16, bT, out);
  } else if (ws_size >= one) {
    unsigned short* b16 = (unsigned short*)d_ws;
    conv_b16<<<4096, 256, 0, stream>>>(b, b16);
    attn_fused<true><<<grid, block, 0, stream>>>(a, b, b16, out);
  } else {
    attn_fused<false><<<grid, block, 0, stream>>>(a, b, nullptr, out);
  }
}

// Round 7
// 217.778 us; speedup vs baseline: 1.7382x; 1.6473x over previous
//
#include <hip/hip_runtime.h>
#include <hip/hip_bf16.h>

#define D 512
#define NSEQ 2048
#define NB 8
#define QBLK 32
#define KVBLK 64
#define NTHREADS 512
#define NT (NSEQ / KVBLK)          // 32 kv tiles
#define ROWE 2056                  // subtiled layout: elems per 4-kv-row group
#define BUFE (16 * ROWE)           // 32896 elems = 65792 B per Bs buffer
#define SROWP (KVBLK + 4)          // f32 row for Ss
#define PROWP (KVBLK + 8)          // bf16 row for Ps

typedef __attribute__((ext_vector_type(8))) short bf16x8;
typedef __attribute__((ext_vector_type(4))) float f32x4;

static __device__ __forceinline__ unsigned short f2b(float f) {
  unsigned u = __builtin_bit_cast(unsigned, f);
  return (unsigned short)((u + 0x7FFFu + ((u >> 16) & 1u)) >> 16);
}

// ---------------- conv: fp32 B -> b16 [kv][d] (memory-bound, ~10us) ---------
__global__ __launch_bounds__(256) void conv_b16(const float* __restrict__ in,
                                                unsigned short* __restrict__ out) {
  size_t i = ((size_t)blockIdx.x * 256 + threadIdx.x) * 8;
  float4 v0 = *reinterpret_cast<const float4*>(in + i);
  float4 v1 = *reinterpret_cast<const float4*>(in + i + 4);
  bf16x8 h;
  h[0] = (short)f2b(v0.x); h[1] = (short)f2b(v0.y);
  h[2] = (short)f2b(v0.z); h[3] = (short)f2b(v0.w);
  h[4] = (short)f2b(v1.x); h[5] = (short)f2b(v1.y);
  h[6] = (short)f2b(v1.z); h[7] = (short)f2b(v1.w);
  *reinterpret_cast<bf16x8*>(out + i) = h;
}

// ---------------------------- v7 main kernel --------------------------------
// r6 post-mortem: latency-bound at 1 block/CU (both pipes <10%, 13K cy/tile vs
// 320 needed). v7 = the r3 structure (fastest verified, 217us) with Bs
// SINGLE-buffered: LDS 145KB -> 79.5KB -> 2 blocks/CU co-resident, so the
// sibling block's compute covers barrier/softmax/DMA stalls (m114 overlap).
// Cost: staging DMA exposed between PV(kt) and QK^T(kt+1) (~L2 latency),
// covered by the sibling. __launch_bounds__(512,4) caps VGPR at 128 (r3
// needed 100) so 16 waves/CU fit the VGPR halving point exactly.
// LDS: Bs 65792 + Ss 8704 + Ps 4608 + stats 384 = 79488 B.
__global__ __launch_bounds__(NTHREADS, 4)
void attn_v7(const float* __restrict__ A, const unsigned short* __restrict__ B16,
             float* __restrict__ Out) {
  __shared__ __align__(16) unsigned short Bs[BUFE];
  __shared__ float Ss[QBLK * SROWP];
  __shared__ unsigned short Ps[QBLK * PROWP];
  __shared__ float mS[QBLK];
  __shared__ float lS[QBLK];
  __shared__ float aS[QBLK];

  const int tid  = threadIdx.x;
  const int wid  = tid >> 6;
  const int lane = tid & 63;
  const int l16  = lane & 15;
  const int g4   = lane >> 4;

  const int batch = blockIdx.x & 7;       // batch -> XCD (L2 locality for b panel)
  const int qt    = blockIdx.x >> 3;
  const int qbase = qt * QBLK;

  const float*          Ab   = A   + (size_t)batch * NSEQ * D;
  const unsigned short* Bb16 = B16 + (size_t)batch * NSEQ * D;
  float*                Ob   = Out + (size_t)batch * NSEQ * D;

  const float scale = 0.04419417382415922f;  // 1/sqrt(512)

  const int qi = wid >> 2;   // wave's q 16-tile for QK^T
  const int ki = wid & 3;    // wave's kv 16-tile for QK^T

  // ---- Q tile into registers (pre-scaled), 16 frags x 8 bf16 ----
  const float* Arow = Ab + (size_t)(qbase + qi * 16 + l16) * D;
  bf16x8 qf[16];
  #pragma unroll
  for (int ks = 0; ks < 16; ++ks) {
    int d0 = ks * 32 + g4 * 8;
    float4 v0 = *reinterpret_cast<const float4*>(Arow + d0);
    float4 v1 = *reinterpret_cast<const float4*>(Arow + d0 + 4);
    bf16x8 f;
    f[0] = (short)f2b(v0.x * scale); f[1] = (short)f2b(v0.y * scale);
    f[2] = (short)f2b(v0.z * scale); f[3] = (short)f2b(v0.w * scale);
    f[4] = (short)f2b(v1.x * scale); f[5] = (short)f2b(v1.y * scale);
    f[6] = (short)f2b(v1.z * scale); f[7] = (short)f2b(v1.w * scale);
    qf[ks] = f;
  }
  if (tid < QBLK) { mS[tid] = -1e30f; lS[tid] = 0.f; }

  f32x4 acc[2][4];
  #pragma unroll
  for (int mi = 0; mi < 2; ++mi)
    #pragma unroll
    for (int ni = 0; ni < 4; ++ni)
      acc[mi][ni] = (f32x4){0.f, 0.f, 0.f, 0.f};

  // ---- prologue: DMA tile 0 -> Bs, drain, barrier ----
  #pragma unroll
  for (int c = 0; c < 8; ++c) {
    int id = wid * 8 + c;
    int g = id >> 2, q = id & 3;
    const unsigned short* src = Bb16
        + (size_t)(g * 4 + ((lane >> 1) & 3)) * D
        + q * 128 + (lane >> 3) * 16 + (lane & 1) * 8;
    unsigned short* dst = &Bs[g * ROWE + q * 512];
    __builtin_amdgcn_global_load_lds(
        (const __attribute__((address_space(1))) void*)src,
        (__attribute__((address_space(3))) void*)dst, 16, 0, 0);
  }
  asm volatile("s_waitcnt vmcnt(0)" ::: "memory");
  asm volatile("s_waitcnt lgkmcnt(0)" ::: "memory");   // Qs stats init too
  __builtin_amdgcn_s_barrier();

  for (int kt = 0; kt < NT; ++kt) {
    // ---- QK^T: wave (qi,ki), Q from regs, B via b128 from subtiled LDS ----
    {
      f32x4 s = {0.f, 0.f, 0.f, 0.f};
      const int bbase = (ki * 4 + (l16 >> 2)) * ROWE + (l16 & 3) * 16 + (g4 & 1) * 8;
      __builtin_amdgcn_s_setprio(1);
      #pragma unroll
      for (int ks = 0; ks < 16; ++ks) {
        const bf16x8 bf = *reinterpret_cast<const bf16x8*>(
            &Bs[bbase + (ks * 2 + (g4 >> 1)) * 64]);
        s = __builtin_amdgcn_mfma_f32_16x16x32_bf16(qf[ks], bf, s, 0, 0, 0);
      }
      __builtin_amdgcn_s_setprio(0);
      #pragma unroll
      for (int r = 0; r < 4; ++r)
        Ss[(qi * 16 + g4 * 4 + r) * SROWP + ki * 16 + l16] = s[r];
    }
    asm volatile("s_waitcnt lgkmcnt(0)" ::: "memory");
    __builtin_amdgcn_s_barrier();

    // ---- online softmax: wave w owns rows 4w..4w+3 ----
    {
      int row = wid * 4 + g4;
      float sv[4];
      float mloc = -1e30f;
      #pragma unroll
      for (int j = 0; j < 4; ++j) {
        sv[j] = Ss[row * SROWP + l16 + 16 * j];
        mloc = fmaxf(mloc, sv[j]);
      }
      #pragma unroll
      for (int off = 1; off < 16; off <<= 1)
        mloc = fmaxf(mloc, __shfl_xor(mloc, off));
      float mold = mS[row];
      float mnew = fmaxf(mold, mloc);
      float al = __expf(mold - mnew);
      float psum = 0.f;
      #pragma unroll
      for (int j = 0; j < 4; ++j) {
        float p = __expf(sv[j] - mnew);
        psum += p;
        Ps[row * PROWP + l16 + 16 * j] = f2b(p);
      }
      #pragma unroll
      for (int off = 1; off < 16; off <<= 1)
        psum += __shfl_xor(psum, off);
      if (l16 == 0) {
        mS[row] = mnew;
        lS[row] = lS[row] * al + psum;
        aS[row] = al;
      }
    }
    asm volatile("s_waitcnt lgkmcnt(0)" ::: "memory");
    __builtin_amdgcn_s_barrier();

    // ---- rescale acc + PV: wave owns d-slice [wid*64, +64) ----
    {
      float alv[2][4];
      #pragma unroll
      for (int mi = 0; mi < 2; ++mi)
        #pragma unroll
        for (int r = 0; r < 4; ++r)
          alv[mi][r] = aS[mi * 16 + g4 * 4 + r];
      #pragma unroll
      for (int mi = 0; mi < 2; ++mi)
        #pragma unroll
        for (int ni = 0; ni < 4; ++ni)
          #pragma unroll
          for (int r = 0; r < 4; ++r)
            acc[mi][ni][r] *= alv[mi][r];

      const unsigned short* Bc = &Bs[0];
      __builtin_amdgcn_s_setprio(1);
      #pragma unroll
      for (int ks = 0; ks < 2; ++ks) {
        bf16x8 pf[2];
        #pragma unroll
        for (int mi = 0; mi < 2; ++mi)
          pf[mi] = *reinterpret_cast<const bf16x8*>(
              &Ps[(mi * 16 + l16) * PROWP + ks * 32 + g4 * 8]);
        #pragma unroll
        for (int ni = 0; ni < 4; ++ni) {
          bf16x8 vv;
          #pragma unroll
          for (int j = 0; j < 8; ++j)
            vv[j] = (short)Bc[(ks * 8 + g4 * 2 + (j >> 2)) * ROWE
                              + (wid * 4 + ni) * 64 + (j & 3) * 16 + l16];
          #pragma unroll
          for (int mi = 0; mi < 2; ++mi)
            acc[mi][ni] = __builtin_amdgcn_mfma_f32_16x16x32_bf16(pf[mi], vv, acc[mi][ni], 0, 0, 0);
        }
      }
      __builtin_amdgcn_s_setprio(0);
    }

    // ---- all PV reads of Bs done across the block -> safe to overwrite ----
    __builtin_amdgcn_s_barrier();
    if (kt + 1 < NT) {
      const unsigned short* Bt = Bb16 + (size_t)(kt + 1) * KVBLK * D;
      #pragma unroll
      for (int c = 0; c < 8; ++c) {
        int id = wid * 8 + c;
        int g = id >> 2, q = id & 3;
        const unsigned short* src = Bt
            + (size_t)(g * 4 + ((lane >> 1) & 3)) * D
            + q * 128 + (lane >> 3) * 16 + (lane & 1) * 8;
        unsigned short* dst = &Bs[g * ROWE + q * 512];
        __builtin_amdgcn_global_load_lds(
            (const __attribute__((address_space(1))) void*)src,
            (__attribute__((address_space(3))) void*)dst, 16, 0, 0);
      }
      asm volatile("s_waitcnt vmcnt(0)" ::: "memory");
    }
    __builtin_amdgcn_s_barrier();     // Bs(kt+1) ready for all waves
  }

  // ---- epilogue: out = acc / l + a ----
  float rl[2][4];
  #pragma unroll
  for (int mi = 0; mi < 2; ++mi)
    #pragma unroll
    for (int r = 0; r < 4; ++r)
      rl[mi][r] = 1.0f / lS[mi * 16 + g4 * 4 + r];
  #pragma unroll
  for (int mi = 0; mi < 2; ++mi)
    #pragma unroll
    for (int ni = 0; ni < 4; ++ni)
      #pragma unroll
      for (int r = 0; r < 4; ++r) {
        int q = qbase + mi * 16 + g4 * 4 + r;
        int d = wid * 64 + ni * 16 + l16;
        size_t off = (size_t)q * D + d;
        Ob[off] = acc[mi][ni][r] * rl[mi][r] + Ab[off];
      }
}

// ---------- fallback: in-kernel convert staging (no workspace) --------------
__global__ __launch_bounds__(NTHREADS, 2)
void attn_fb(const float* __restrict__ A, const float* __restrict__ B32,
             float* __restrict__ Out) {
  __shared__ __align__(16) unsigned short Bs[BUFE];
  __shared__ float Ss[QBLK * SROWP];
  __shared__ unsigned short Ps[QBLK * PROWP];
  __shared__ float mS[QBLK];
  __shared__ float lS[QBLK];
  __shared__ float aS[QBLK];

  const int tid  = threadIdx.x;
  const int wid  = tid >> 6;
  const int lane = tid & 63;
  const int l16  = lane & 15;
  const int g4   = lane >> 4;

  const int batch = blockIdx.x & 7;
  const int qt    = blockIdx.x >> 3;
  const int qbase = qt * QBLK;

  const float* Ab   = A   + (size_t)batch * NSEQ * D;
  const float* Bb32 = B32 + (size_t)batch * NSEQ * D;
  float*       Ob   = Out + (size_t)batch * NSEQ * D;

  const float scale = 0.04419417382415922f;

  const int qi = wid >> 2;
  const int ki = wid & 3;

  const float* Arow = Ab + (size_t)(qbase + qi * 16 + l16) * D;
  bf16x8 qf[16];
  #pragma unroll
  for (int ks = 0; ks < 16; ++ks) {
    int d0 = ks * 32 + g4 * 8;
    float4 v0 = *reinterpret_cast<const float4*>(Arow + d0);
    float4 v1 = *reinterpret_cast<const float4*>(Arow + d0 + 4);
    bf16x8 f;
    f[0] = (short)f2b(v0.x * scale); f[1] = (short)f2b(v0.y * scale);
    f[2] = (short)f2b(v0.z * scale); f[3] = (short)f2b(v0.w * scale);
    f[4] = (short)f2b(v1.x * scale); f[5] = (short)f2b(v1.y * scale);
    f[6] = (short)f2b(v1.z * scale); f[7] = (short)f2b(v1.w * scale);
    qf[ks] = f;
  }
  if (tid < QBLK) { mS[tid] = -1e30f; lS[tid] = 0.f; }

  f32x4 acc[2][4];
  #pragma unroll
  for (int mi = 0; mi < 2; ++mi)
    #pragma unroll
    for (int ni = 0; ni < 4; ++ni)
      acc[mi][ni] = (f32x4){0.f, 0.f, 0.f, 0.f};

  for (int kt = 0; kt < NT; ++kt) {
    __builtin_amdgcn_s_barrier();
    const float* Bt = Bb32 + (size_t)kt * KVBLK * D;
    #pragma unroll
    for (int c = 0; c < 8; ++c) {
      int id = wid * 8 + c;
      int g = id >> 2, q = id & 3;
      int kv = g * 4 + ((lane >> 1) & 3);
      int d  = q * 128 + (lane >> 3) * 16 + (lane & 1) * 8;
      const float* s = Bt + (size_t)kv * D + d;
      float4 v0 = *reinterpret_cast<const float4*>(s);
      float4 v1 = *reinterpret_cast<const float4*>(s + 4);
      bf16x8 h;
      h[0] = (short)f2b(v0.x); h[1] = (short)f2b(v0.y);
      h[2] = (short)f2b(v0.z); h[3] = (short)f2b(v0.w);
      h[4] = (short)f2b(v1.x); h[5] = (short)f2b(v1.y);
      h[6] = (short)f2b(v1.z); h[7] = (short)f2b(v1.w);
      *reinterpret_cast<bf16x8*>(&Bs[g * ROWE + q * 512 + lane * 8]) = h;
    }
    asm volatile("s_waitcnt lgkmcnt(0)" ::: "memory");
    __builtin_amdgcn_s_barrier();

    {
      f32x4 s = {0.f, 0.f, 0.f, 0.f};
      const int bbase = (ki * 4 + (l16 >> 2)) * ROWE + (l16 & 3) * 16 + (g4 & 1) * 8;
      #pragma unroll
      for (int ks = 0; ks < 16; ++ks) {
        const bf16x8 bf = *reinterpret_cast<const bf16x8*>(
            &Bs[bbase + (ks * 2 + (g4 >> 1)) * 64]);
        s = __builtin_amdgcn_mfma_f32_16x16x32_bf16(qf[ks], bf, s, 0, 0, 0);
      }
      #pragma unroll
      for (int r = 0; r < 4; ++r)
        Ss[(qi * 16 + g4 * 4 + r) * SROWP + ki * 16 + l16] = s[r];
    }
    asm volatile("s_waitcnt lgkmcnt(0)" ::: "memory");
    __builtin_amdgcn_s_barrier();

    {
      int row = wid * 4 + g4;
      float sv[4];
      float mloc = -1e30f;
      #pragma unroll
      for (int j = 0; j < 4; ++j) {
        sv[j] = Ss[row * SROWP + l16 + 16 * j];
        mloc = fmaxf(mloc, sv[j]);
      }
      #pragma unroll
      for (int off = 1; off < 16; off <<= 1)
        mloc = fmaxf(mloc, __shfl_xor(mloc, off));
      float mold = mS[row];
      float mnew = fmaxf(mold, mloc);
      float al = __expf(mold - mnew);
      float psum = 0.f;
      #pragma unroll
      for (int j = 0; j < 4; ++j) {
        float p = __expf(sv[j] - mnew);
        psum += p;
        Ps[row * PROWP + l16 + 16 * j] = f2b(p);
      }
      #pragma unroll
      for (int off = 1; off < 16; off <<= 1)
        psum += __shfl_xor(psum, off);
      if (l16 == 0) {
        mS[row] = mnew;
        lS[row] = lS[row] * al + psum;
        aS[row] = al;
      }
    }
    asm volatile("s_waitcnt lgkmcnt(0)" ::: "memory");
    __builtin_amdgcn_s_barrier();

    {
      float alv[2][4];
      #pragma unroll
      for (int mi = 0; mi < 2; ++mi)
        #pragma unroll
        for (int r = 0; r < 4; ++r)
          alv[mi][r] = aS[mi * 16 + g4 * 4 + r];
      #pragma unroll
      for (int mi = 0; mi < 2; ++mi)
        #pragma unroll
        for (int ni = 0; ni < 4; ++ni)
          #pragma unroll
          for (int r = 0; r < 4; ++r)
            acc[mi][ni][r] *= alv[mi][r];

      #pragma unroll
      for (int ks = 0; ks < 2; ++ks) {
        bf16x8 pf[2];
        #pragma unroll
        for (int mi = 0; mi < 2; ++mi)
          pf[mi] = *reinterpret_cast<const bf16x8*>(
              &Ps[(mi * 16 + l16) * PROWP + ks * 32 + g4 * 8]);
        #pragma unroll
        for (int ni = 0; ni < 4; ++ni) {
          bf16x8 vv;
          #pragma unroll
          for (int j = 0; j < 8; ++j)
            vv[j] = (short)Bs[(ks * 8 + g4 * 2 + (j >> 2)) * ROWE
                              + (wid * 4 + ni) * 64 + (j & 3) * 16 + l16];
          #pragma unroll
          for (int mi = 0; mi < 2; ++mi)
            acc[mi][ni] = __builtin_amdgcn_mfma_f32_16x16x32_bf16(pf[mi], vv, acc[mi][ni], 0, 0, 0);
        }
      }
    }
  }

  float rl[2][4];
  #pragma unroll
  for (int mi = 0; mi < 2; ++mi)
    #pragma unroll
    for (int r = 0; r < 4; ++r)
      rl[mi][r] = 1.0f / lS[mi * 16 + g4 * 4 + r];
  #pragma unroll
  for (int mi = 0; mi < 2; ++mi)
    #pragma unroll
    for (int ni = 0; ni < 4; ++ni)
      #pragma unroll
      for (int r = 0; r < 4; ++r) {
        int q = qbase + mi * 16 + g4 * 4 + r;
        int d = wid * 64 + ni * 16 + l16;
        size_t off = (size_t)q * D + d;
        Ob[off] = acc[mi][ni][r] * rl[mi][r] + Ab[off];
      }
}

extern "C" void kernel_launch(void* const* d_in, const int* in_sizes, int n_in,
                              void* d_out, int out_size, void* d_ws, size_t ws_size,
                              hipStream_t stream) {
  const float* a = (const float*)d_in[0];
  const float* b = (const float*)d_in[1];
  float* out = (float*)d_out;
  const size_t need = (size_t)NB * NSEQ * D * sizeof(unsigned short);  // 16 MB
  dim3 grid(NB * (NSEQ / QBLK));
  dim3 block(NTHREADS);
  if (ws_size >= need) {
    unsigned short* b16 = (unsigned short*)d_ws;
    conv_b16<<<4096, 256, 0, stream>>>(b, b16);
    attn_v7<<<grid, block, 0, stream>>>(a, b16, out);
  } else {
    attn_fb<<<grid, block, 0, stream>>>(a, b, out);
  }
}